// Round 6
// baseline (127.904 us; speedup 1.0000x reference)
//
#include <hip/hip_runtime.h>
#include <hip/hip_bf16.h>

typedef unsigned short u16;
typedef float f32x4 __attribute__((ext_vector_type(4)));
typedef __bf16 bf16x8 __attribute__((ext_vector_type(8)));
typedef u16 u16x8 __attribute__((ext_vector_type(8)));

#define M_DIM 16384
#define IN_DIM 1024
#define OUT_DIM 1024
#define K_KNOTS 12
#define KCAT 2048   // concatenated K dimension

// Fragment-tiled global layout for A and B (the key change this round):
//   X_tiled[(g16*64 + kc)*512 + l*8 + e] = X[g16*16 + (l&15)][kc*32 + (l>>4)*8 + e]
// so one wave's global_load_lds (lane*16B) stages exactly one MFMA frag from a
// CONTIGUOUS 1KB global range (was: 16 x 64B segments at 4KB stride).

// ---- helpers ----
__device__ __forceinline__ u16 f2bf(float f) {
    unsigned int u = __builtin_bit_cast(unsigned int, f);
    u = u + 0x7FFFu + ((u >> 16) & 1u);   // RNE
    return (u16)(u >> 16);
}

__device__ __forceinline__ void gload_lds16(const void* g, void* l) {
    __builtin_amdgcn_global_load_lds(
        (const __attribute__((address_space(1))) unsigned int*)g,
        (__attribute__((address_space(3))) unsigned int*)l, 16, 0, 0);
}

// ---- kernel 1: per-feature knot prep (sort + sigmoid mask) ----
__global__ void prep_kernel(const float* __restrict__ grid,
                            const float* __restrict__ coeffs,
                            const float* __restrict__ alive,
                            float* __restrict__ pmc,     // [IN][12]
                            float* __restrict__ pgmin,   // [IN]
                            float* __restrict__ pscale)  // [IN]
{
    int i = blockIdx.x * blockDim.x + threadIdx.x;
    if (i >= IN_DIM) return;
    float g[K_KNOTS], c[K_KNOTS], a[K_KNOTS];
    for (int k = 0; k < K_KNOTS; ++k) {
        g[k] = grid[i * K_KNOTS + k];
        c[k] = coeffs[i * K_KNOTS + k];
        a[k] = alive[i * K_KNOTS + k];
    }
    for (int k = 1; k < K_KNOTS; ++k) {
        float gk = g[k], ck = c[k], ak = a[k];
        int j = k - 1;
        while (j >= 0 && g[j] > gk) {
            g[j + 1] = g[j]; c[j + 1] = c[j]; a[j + 1] = a[j]; --j;
        }
        g[j + 1] = gk; c[j + 1] = ck; a[j + 1] = ak;
    }
    for (int k = 0; k < K_KNOTS; ++k)
        pmc[i * K_KNOTS + k] = c[k] / (1.0f + expf(-a[k]));
    pgmin[i] = g[0];
    pscale[i] = (float)(K_KNOTS - 1) / fmaxf(g[K_KNOTS - 1] - g[0], 1e-6f);
}

// ---- kernel 2: pack [proj_w | res_w] into frag-tiled bf16 B (64 n16-groups) ----
__global__ __launch_bounds__(256) void conv_w_kernel(
    const float* __restrict__ pw, const float* __restrict__ rw,
    u16* __restrict__ Bw)
{
    const int n16 = blockIdx.x;       // 0..63
    const int tid = threadIdx.x;
    #pragma unroll 1
    for (int j = 0; j < 16; ++j) {
        int s = j * 256 + tid;        // 0..4095
        int kc = s >> 6, l = s & 63;
        int row = n16 * 16 + (l & 15);
        int k = kc * 32 + ((l >> 4) & 3) * 8;
        const float* src = (k < IN_DIM) ? &pw[(long)row * IN_DIM + k]
                                        : &rw[(long)row * IN_DIM + (k - IN_DIM)];
        float4 v0 = *(const float4*)src;
        float4 v1 = *(const float4*)(src + 4);
        u16x8 ov;
        ov[0] = f2bf(v0.x); ov[1] = f2bf(v0.y); ov[2] = f2bf(v0.z); ov[3] = f2bf(v0.w);
        ov[4] = f2bf(v1.x); ov[5] = f2bf(v1.y); ov[6] = f2bf(v1.z); ov[7] = f2bf(v1.w);
        *(u16x8*)&Bw[((long)n16 * 64 + kc) * 512 + l * 8] = ov;
    }
}

// ---- kernel 3: build A = [spline(x) | x] in frag-tiled bf16 ----
__global__ __launch_bounds__(256) void build_a_kernel(
    const float* __restrict__ x,
    const float* __restrict__ pmc,
    const float* __restrict__ pgmin,
    const float* __restrict__ pscale,
    u16* __restrict__ Abf)
{
    __shared__ float s_mc[IN_DIM * K_KNOTS];
    __shared__ float s_gmin[IN_DIM];
    __shared__ float s_scale[IN_DIM];
    const int tid = threadIdx.x;
    for (int i = tid; i < IN_DIM * K_KNOTS; i += 256) s_mc[i] = pmc[i];
    for (int i = tid; i < IN_DIM; i += 256) { s_gmin[i] = pgmin[i]; s_scale[i] = pscale[i]; }
    __syncthreads();

    const int m16 = blockIdx.x;   // 0..1023
    #pragma unroll 1
    for (int j = 0; j < 16; ++j) {
        int s = j * 256 + tid;    // 0..4095
        int kc = s >> 6, l = s & 63;
        int row = m16 * 16 + (l & 15);
        int k = kc * 32 + ((l >> 4) & 3) * 8;
        const bool sp = (k < IN_DIM);
        const float* xr = &x[(long)row * IN_DIM + (sp ? k : k - IN_DIM)];
        float4 v0 = *(const float4*)xr;
        float4 v1 = *(const float4*)(xr + 4);
        float xs[8] = {v0.x, v0.y, v0.z, v0.w, v1.x, v1.y, v1.z, v1.w};
        u16x8 ov;
        if (sp) {
            #pragma unroll
            for (int e = 0; e < 8; ++e) {
                int i = k + e;
                float xx = xs[e];
                float xn = (xx - s_gmin[i]) * s_scale[i];
                xn = fminf(fmaxf(xn, 0.0f), (float)(K_KNOTS - 1));
                int li = (int)xn;
                if (li > K_KNOTS - 2) li = K_KNOTS - 2;
                float frac = xn - (float)li;
                float cl = s_mc[i * K_KNOTS + li];
                float cr = s_mc[i * K_KNOTS + li + 1];
                ov[e] = f2bf(cl + frac * (cr - cl));
            }
        } else {
            #pragma unroll
            for (int e = 0; e < 8; ++e) ov[e] = f2bf(xs[e]);
        }
        *(u16x8*)&Abf[((long)m16 * 64 + kc) * 512 + l * 8] = ov;
    }
}

// ---- kernel 4: 256x256 bf16 GEMM, 8-phase / 2-K-tile schedule ----
// Identical schedule to R5; ONLY staging source addressing changed to the
// frag-tiled layout (contiguous 1KB per gload_lds). LDS content identical.
#define TBK 64
#define NT (KCAT / TBK)   // 32 K-tiles, 16 iterations
#define MSTR 32768L       // m16/n16-group stride in tiled layout (64 kc * 512)

#define BAR()     asm volatile("s_barrier" ::: "memory")
#define VM6BAR()  asm volatile("s_waitcnt vmcnt(6)\ns_barrier" ::: "memory")
#define LGKM0()   do { asm volatile("s_waitcnt lgkmcnt(0)" ::: "memory"); \
                       __builtin_amdgcn_sched_barrier(0); } while (0)

#define READ_A(buf, kk, mh) \
    _Pragma("unroll") \
    for (int m_ = 0; m_ < 4; ++m_) \
        af[m_] = *(const bf16x8*)&lds[(buf) + (kk)*8192 + (wm*8 + (mh)*4 + m_)*512 + loff];

#define READ_B(buf, kk) \
    _Pragma("unroll") \
    for (int n_ = 0; n_ < 4; ++n_) \
        bfr[n_] = *(const bf16x8*)&lds[32768 + (buf) + (kk)*8192 + (wn*4 + n_)*512 + loff];

#define MFMA16(base) \
    __builtin_amdgcn_s_setprio(1); \
    _Pragma("unroll") \
    for (int m_ = 0; m_ < 4; ++m_) \
        _Pragma("unroll") \
        for (int n_ = 0; n_ < 4; ++n_) \
            acc[(base) + m_][n_] = __builtin_amdgcn_mfma_f32_16x16x32_bf16( \
                af[m_], bfr[n_], acc[(base) + m_][n_], 0, 0, 0); \
    __builtin_amdgcn_s_setprio(0);

// Tidx = K-tile index; kc = Tidx*2+kk. Wave w stages frag w (d0) and w+8 (d1).
#define STAGE_A(Tidx, kk, buf) do { \
    gload_lds16(pAf +          ((long)((Tidx)*2 + (kk))) * 512, &lds[(buf) + (kk)*8192 + d0]); \
    gload_lds16(pAf + 8*MSTR + ((long)((Tidx)*2 + (kk))) * 512, &lds[(buf) + (kk)*8192 + d1]); } while (0)
#define STAGE_B(Tidx, kk, buf) do { \
    gload_lds16(pBf +          ((long)((Tidx)*2 + (kk))) * 512, &lds[32768 + (buf) + (kk)*8192 + d0]); \
    gload_lds16(pBf + 8*MSTR + ((long)((Tidx)*2 + (kk))) * 512, &lds[32768 + (buf) + (kk)*8192 + d1]); } while (0)

__global__ __launch_bounds__(512, 2) void gemm_kernel(
    const u16* __restrict__ A,   // frag-tiled, 1024 m16-groups
    const u16* __restrict__ B,   // frag-tiled, 64 n16-groups
    const float* __restrict__ bias,
    float* __restrict__ C)
{
    // LDS element map (u16 units): A buf0 @0, A buf1 @16384; B buf0 @32768,
    // B buf1 @49152. unit kk: +kk*8192 ; frag f: +f*512 ; lane l: elem l*8.
    __shared__ __align__(16) u16 lds[65536];   // 128 KiB

    const int tid  = threadIdx.x;
    const int lane = tid & 63;
    const int wave = tid >> 6;
    const int wm   = wave >> 2;   // 0..1
    const int wn   = wave & 3;    // 0..3

    // bijective XCD swizzle (nwg = 256)
    int wgid = (blockIdx.x & 7) * 32 + (blockIdx.x >> 3);
    const int brow = (wgid >> 2) * 256;
    const int bcol = (wgid & 3) * 256;

    // contiguous staging source: wave w's frag pointer (m16 = brow/16 + w)
    const u16* pAf = A + ((long)(brow >> 4) + wave) * MSTR + lane * 8;
    const u16* pBf = B + ((long)(bcol >> 4) + wave) * MSTR + lane * 8;

    const int d0 = tid * 8;          // frag 'wave'   dest within unit
    const int d1 = 4096 + tid * 8;   // frag 'wave+8' dest within unit
    const int loff = lane * 8;       // lane-order frag read

    f32x4 acc[8][4] = {};
    bf16x8 af[4], bfr[4];

    // prologue: queue order A0(0),B0(0),A1(0),B1(0),B0(1),A0(1),B1(1)
    STAGE_A(0, 0, 0);
    STAGE_B(0, 0, 0);
    STAGE_A(0, 1, 0);
    STAGE_B(0, 1, 0);
    STAGE_B(1, 0, 16384);
    STAGE_A(1, 0, 16384);
    STAGE_B(1, 1, 16384);
    VM6BAR();   // tile-0 units complete; {B0,A0,B1}(1) may remain in flight

    #pragma unroll 1
    for (int t = 0; t < NT / 2; ++t) {
        const int T  = 2 * t;
        const int T1 = T + 1;
        const int T2 = (T + 2 < NT) ? T + 2 : 0;  // wrap: staged, never read
        const int T3 = (T + 3 < NT) ? T + 3 : 0;

        // ---- Ph1: tile T (buf0) mh0 kk0 ; stage A1(T+1) ----
        READ_A(0, 0, 0); READ_B(0, 0);
        STAGE_A(T1, 1, 16384);
        BAR(); LGKM0();
        MFMA16(0);
        BAR();

        // ---- Ph2: tile T mh1 kk0 ; stage B0(T+2) ----
        READ_A(0, 0, 1);
        STAGE_B(T2, 0, 0);
        BAR(); LGKM0();
        MFMA16(4);
        BAR();

        // ---- Ph3: tile T mh0 kk1 ; stage A0(T+2) ----
        READ_A(0, 1, 0); READ_B(0, 1);
        STAGE_A(T2, 0, 0);
        BAR(); LGKM0();
        MFMA16(0);
        BAR();

        // ---- Ph4: tile T mh1 kk1 ; stage B1(T+2) ; vmcnt publishes tile T+1 ----
        READ_A(0, 1, 1);
        STAGE_B(T2, 1, 0);
        VM6BAR(); LGKM0();
        MFMA16(4);
        BAR();

        // ---- Ph5: tile T+1 (buf1) mh0 kk0 ; stage A1(T+2) ----
        READ_A(16384, 0, 0); READ_B(16384, 0);
        STAGE_A(T2, 1, 0);
        BAR(); LGKM0();
        MFMA16(0);
        BAR();

        // ---- Ph6: tile T+1 mh1 kk0 ; stage B0(T+3) ----
        READ_A(16384, 0, 1);
        STAGE_B(T3, 0, 16384);
        BAR(); LGKM0();
        MFMA16(4);
        BAR();

        // ---- Ph7: tile T+1 mh0 kk1 ; stage A0(T+3) ----
        READ_A(16384, 1, 0); READ_B(16384, 1);
        STAGE_A(T3, 0, 16384);
        BAR(); LGKM0();
        MFMA16(0);
        BAR();

        // ---- Ph8: tile T+1 mh1 kk1 ; stage B1(T+3) ; vmcnt publishes tile T+2 ----
        READ_A(16384, 1, 1);
        STAGE_B(T3, 1, 16384);
        VM6BAR(); LGKM0();
        MFMA16(4);
        BAR();
    }

    // ---- epilogue ----
    const int crow0 = brow + wm * 128 + (lane >> 4) * 4;
    const int ccol0 = bcol + wn * 64 + (lane & 15);
    float bv[4];
    #pragma unroll
    for (int n = 0; n < 4; ++n) bv[n] = bias[ccol0 + n * 16];
    #pragma unroll
    for (int m = 0; m < 8; ++m) {
        #pragma unroll
        for (int n = 0; n < 4; ++n) {
            #pragma unroll
            for (int j = 0; j < 4; ++j) {
                int row = crow0 + m * 16 + j;
                C[(long)row * OUT_DIM + ccol0 + n * 16] = acc[m][n][j] + bv[n];
            }
        }
    }
}

extern "C" void kernel_launch(void* const* d_in, const int* in_sizes, int n_in,
                              void* d_out, int out_size, void* d_ws, size_t ws_size,
                              hipStream_t stream) {
    const float* x      = (const float*)d_in[0];
    const float* grid   = (const float*)d_in[1];
    const float* coeffs = (const float*)d_in[2];
    const float* alive  = (const float*)d_in[3];
    const float* proj_w = (const float*)d_in[4];
    const float* proj_b = (const float*)d_in[5];
    const float* res_w  = (const float*)d_in[6];
    float* out = (float*)d_out;

    char* w = (char*)d_ws;
    size_t a_bytes = (size_t)M_DIM * KCAT * sizeof(u16);     // 64 MiB
    size_t b_bytes = (size_t)OUT_DIM * KCAT * sizeof(u16);   // 4 MiB
    u16* Abf   = (u16*)w;
    u16* Bw    = (u16*)(w + a_bytes);
    float* pmc = (float*)(w + a_bytes + b_bytes);
    float* pgmin  = pmc + IN_DIM * K_KNOTS;
    float* pscale = pgmin + IN_DIM;

    prep_kernel<<<(IN_DIM + 255) / 256, 256, 0, stream>>>(grid, coeffs, alive,
                                                          pmc, pgmin, pscale);
    conv_w_kernel<<<OUT_DIM / 16, 256, 0, stream>>>(proj_w, res_w, Bw);
    build_a_kernel<<<M_DIM / 16, 256, 0, stream>>>(x, pmc, pgmin, pscale, Abf);
    gemm_kernel<<<(M_DIM / 256) * (OUT_DIM / 256), 512, 0, stream>>>(Abf, Bw, proj_b, out);
}

// Round 7
// 114.735 us; speedup vs baseline: 1.1148x; 1.1148x over previous
//
#include <hip/hip_runtime.h>
#include <hip/hip_bf16.h>

typedef unsigned short u16;
typedef float f32x4 __attribute__((ext_vector_type(4)));
typedef __bf16 bf16x8 __attribute__((ext_vector_type(8)));
typedef u16 u16x8 __attribute__((ext_vector_type(8)));

#define M_DIM 16384
#define IN_DIM 1024
#define OUT_DIM 1024
#define K_KNOTS 12
#define KCAT 2048   // concatenated K dimension

// Fragment-tiled global layout for A and B:
//   X_tiled[(g16*64 + kc)*512 + l*8 + e] = X[g16*16 + (l&15)][kc*32 + (l>>4)*8 + e]
// so one wave's global_load_lds (lane*16B) stages exactly one MFMA frag from a
// CONTIGUOUS 1KB global range.

// ---- helpers ----
__device__ __forceinline__ u16 f2bf(float f) {
    unsigned int u = __builtin_bit_cast(unsigned int, f);
    u = u + 0x7FFFu + ((u >> 16) & 1u);   // RNE
    return (u16)(u >> 16);
}

__device__ __forceinline__ void gload_lds16(const void* g, void* l) {
    __builtin_amdgcn_global_load_lds(
        (const __attribute__((address_space(1))) unsigned int*)g,
        (__attribute__((address_space(3))) unsigned int*)l, 16, 0, 0);
}

// ---- kernel 1: per-feature knot prep (sort + sigmoid mask) ----
__global__ void prep_kernel(const float* __restrict__ grid,
                            const float* __restrict__ coeffs,
                            const float* __restrict__ alive,
                            float* __restrict__ pmc,     // [IN][12]
                            float* __restrict__ pgmin,   // [IN]
                            float* __restrict__ pscale)  // [IN]
{
    int i = blockIdx.x * blockDim.x + threadIdx.x;
    if (i >= IN_DIM) return;
    float g[K_KNOTS], c[K_KNOTS], a[K_KNOTS];
    for (int k = 0; k < K_KNOTS; ++k) {
        g[k] = grid[i * K_KNOTS + k];
        c[k] = coeffs[i * K_KNOTS + k];
        a[k] = alive[i * K_KNOTS + k];
    }
    for (int k = 1; k < K_KNOTS; ++k) {
        float gk = g[k], ck = c[k], ak = a[k];
        int j = k - 1;
        while (j >= 0 && g[j] > gk) {
            g[j + 1] = g[j]; c[j + 1] = c[j]; a[j + 1] = a[j]; --j;
        }
        g[j + 1] = gk; c[j + 1] = ck; a[j + 1] = ak;
    }
    for (int k = 0; k < K_KNOTS; ++k)
        pmc[i * K_KNOTS + k] = c[k] / (1.0f + expf(-a[k]));
    pgmin[i] = g[0];
    pscale[i] = (float)(K_KNOTS - 1) / fmaxf(g[K_KNOTS - 1] - g[0], 1e-6f);
}

// ---- kernel 2: pack [proj_w | res_w] into frag-tiled bf16 B (64 n16-groups) ----
__global__ __launch_bounds__(256) void conv_w_kernel(
    const float* __restrict__ pw, const float* __restrict__ rw,
    u16* __restrict__ Bw)
{
    const int n16 = blockIdx.x;       // 0..63
    const int tid = threadIdx.x;
    #pragma unroll 1
    for (int j = 0; j < 16; ++j) {
        int s = j * 256 + tid;        // 0..4095
        int kc = s >> 6, l = s & 63;
        int row = n16 * 16 + (l & 15);
        int k = kc * 32 + ((l >> 4) & 3) * 8;
        const float* src = (k < IN_DIM) ? &pw[(long)row * IN_DIM + k]
                                        : &rw[(long)row * IN_DIM + (k - IN_DIM)];
        float4 v0 = *(const float4*)src;
        float4 v1 = *(const float4*)(src + 4);
        u16x8 ov;
        ov[0] = f2bf(v0.x); ov[1] = f2bf(v0.y); ov[2] = f2bf(v0.z); ov[3] = f2bf(v0.w);
        ov[4] = f2bf(v1.x); ov[5] = f2bf(v1.y); ov[6] = f2bf(v1.z); ov[7] = f2bf(v1.w);
        *(u16x8*)&Bw[((long)n16 * 64 + kc) * 512 + l * 8] = ov;
    }
}

// ---- kernel 3: build A = [spline(x) | x] in frag-tiled bf16, coalesced ----
// Per block: 16 rows of x. Per 256-col chunk: coalesced row-major load into
// padded LDS tile, then frag-ordered reads from LDS + contiguous 16B stores.
#define XT_STR 260   // 256 + 4 pad floats: rows offset by 4 banks

__global__ __launch_bounds__(256) void build_a_kernel(
    const float* __restrict__ x,
    const float* __restrict__ pmc,
    const float* __restrict__ pgmin,
    const float* __restrict__ pscale,
    u16* __restrict__ Abf)
{
    __shared__ float s_mc[IN_DIM * K_KNOTS];
    __shared__ float s_gmin[IN_DIM];
    __shared__ float s_scale[IN_DIM];
    __shared__ float xt[16 * XT_STR];
    const int tid = threadIdx.x;
    for (int i = tid; i < IN_DIM * K_KNOTS; i += 256) s_mc[i] = pmc[i];
    for (int i = tid; i < IN_DIM; i += 256) { s_gmin[i] = pgmin[i]; s_scale[i] = pscale[i]; }

    const int m16 = blockIdx.x;   // 0..1023

    #pragma unroll 1
    for (int c0 = 0; c0 < IN_DIM; c0 += 256) {
        __syncthreads();   // params ready (iter 0); WAR on xt (iters 1+)

        // phase A: coalesced x load -> xt
        #pragma unroll
        for (int p = 0; p < 4; ++p) {
            int idx = p * 256 + tid;
            int r = idx >> 6, lc = (idx & 63) * 4;
            float4 v = *(const float4*)&x[(long)(m16 * 16 + r) * IN_DIM + c0 + lc];
            *(float4*)&xt[r * XT_STR + lc] = v;
        }
        __syncthreads();

        // phase B: frag-ordered LDS reads, spline + copy, coalesced stores
        #pragma unroll
        for (int p = 0; p < 2; ++p) {
            int s = p * 256 + tid;          // 0..511
            int kc_l = s >> 6, l = s & 63;
            int r = l & 15;
            int cb = kc_l * 32 + ((l >> 4) & 3) * 8;
            const float* xp = &xt[r * XT_STR + cb];
            float4 v0 = *(const float4*)xp;
            float4 v1 = *(const float4*)(xp + 4);
            float xs[8] = {v0.x, v0.y, v0.z, v0.w, v1.x, v1.y, v1.z, v1.w};
            u16x8 so, co;
            #pragma unroll
            for (int e = 0; e < 8; ++e) {
                int i = c0 + cb + e;
                float xx = xs[e];
                float xn = (xx - s_gmin[i]) * s_scale[i];
                xn = fminf(fmaxf(xn, 0.0f), (float)(K_KNOTS - 1));
                int li = (int)xn;
                if (li > K_KNOTS - 2) li = K_KNOTS - 2;
                float frac = xn - (float)li;
                float cl = s_mc[i * K_KNOTS + li];
                float cr = s_mc[i * K_KNOTS + li + 1];
                so[e] = f2bf(cl + frac * (cr - cl));
                co[e] = f2bf(xx);
            }
            long kcS = (long)m16 * 64 + (c0 >> 5) + kc_l;   // spline: k in [0,1024)
            *(u16x8*)&Abf[kcS * 512 + l * 8] = so;
            *(u16x8*)&Abf[(kcS + 32) * 512 + l * 8] = co;   // copy: k in [1024,2048)
        }
    }
}

// ---- kernel 4: 256x256 bf16 GEMM, 8-phase / 2-K-tile schedule ----
// (unchanged from R6 — frag-tiled contiguous staging, conflict-free LDS)
#define TBK 64
#define NT (KCAT / TBK)   // 32 K-tiles, 16 iterations
#define MSTR 32768L       // m16/n16-group stride in tiled layout (64 kc * 512)

#define BAR()     asm volatile("s_barrier" ::: "memory")
#define VM6BAR()  asm volatile("s_waitcnt vmcnt(6)\ns_barrier" ::: "memory")
#define LGKM0()   do { asm volatile("s_waitcnt lgkmcnt(0)" ::: "memory"); \
                       __builtin_amdgcn_sched_barrier(0); } while (0)

#define READ_A(buf, kk, mh) \
    _Pragma("unroll") \
    for (int m_ = 0; m_ < 4; ++m_) \
        af[m_] = *(const bf16x8*)&lds[(buf) + (kk)*8192 + (wm*8 + (mh)*4 + m_)*512 + loff];

#define READ_B(buf, kk) \
    _Pragma("unroll") \
    for (int n_ = 0; n_ < 4; ++n_) \
        bfr[n_] = *(const bf16x8*)&lds[32768 + (buf) + (kk)*8192 + (wn*4 + n_)*512 + loff];

#define MFMA16(base) \
    __builtin_amdgcn_s_setprio(1); \
    _Pragma("unroll") \
    for (int m_ = 0; m_ < 4; ++m_) \
        _Pragma("unroll") \
        for (int n_ = 0; n_ < 4; ++n_) \
            acc[(base) + m_][n_] = __builtin_amdgcn_mfma_f32_16x16x32_bf16( \
                af[m_], bfr[n_], acc[(base) + m_][n_], 0, 0, 0); \
    __builtin_amdgcn_s_setprio(0);

// Tidx = K-tile index; kc = Tidx*2+kk. Wave w stages frag w (d0) and w+8 (d1).
#define STAGE_A(Tidx, kk, buf) do { \
    gload_lds16(pAf +          ((long)((Tidx)*2 + (kk))) * 512, &lds[(buf) + (kk)*8192 + d0]); \
    gload_lds16(pAf + 8*MSTR + ((long)((Tidx)*2 + (kk))) * 512, &lds[(buf) + (kk)*8192 + d1]); } while (0)
#define STAGE_B(Tidx, kk, buf) do { \
    gload_lds16(pBf +          ((long)((Tidx)*2 + (kk))) * 512, &lds[32768 + (buf) + (kk)*8192 + d0]); \
    gload_lds16(pBf + 8*MSTR + ((long)((Tidx)*2 + (kk))) * 512, &lds[32768 + (buf) + (kk)*8192 + d1]); } while (0)

__global__ __launch_bounds__(512, 2) void gemm_kernel(
    const u16* __restrict__ A,   // frag-tiled, 1024 m16-groups
    const u16* __restrict__ B,   // frag-tiled, 64 n16-groups
    const float* __restrict__ bias,
    float* __restrict__ C)
{
    __shared__ __align__(16) u16 lds[65536];   // 128 KiB

    const int tid  = threadIdx.x;
    const int lane = tid & 63;
    const int wave = tid >> 6;
    const int wm   = wave >> 2;   // 0..1
    const int wn   = wave & 3;    // 0..3

    // bijective XCD swizzle (nwg = 256)
    int wgid = (blockIdx.x & 7) * 32 + (blockIdx.x >> 3);
    const int brow = (wgid >> 2) * 256;
    const int bcol = (wgid & 3) * 256;

    // contiguous staging source: wave w's frag pointer (m16 = brow/16 + w)
    const u16* pAf = A + ((long)(brow >> 4) + wave) * MSTR + lane * 8;
    const u16* pBf = B + ((long)(bcol >> 4) + wave) * MSTR + lane * 8;

    const int d0 = tid * 8;          // frag 'wave'   dest within unit
    const int d1 = 4096 + tid * 8;   // frag 'wave+8' dest within unit
    const int loff = lane * 8;       // lane-order frag read

    f32x4 acc[8][4] = {};
    bf16x8 af[4], bfr[4];

    // prologue: queue order A0(0),B0(0),A1(0),B1(0),B0(1),A0(1),B1(1)
    STAGE_A(0, 0, 0);
    STAGE_B(0, 0, 0);
    STAGE_A(0, 1, 0);
    STAGE_B(0, 1, 0);
    STAGE_B(1, 0, 16384);
    STAGE_A(1, 0, 16384);
    STAGE_B(1, 1, 16384);
    VM6BAR();   // tile-0 units complete; {B0,A0,B1}(1) may remain in flight

    #pragma unroll 1
    for (int t = 0; t < NT / 2; ++t) {
        const int T  = 2 * t;
        const int T1 = T + 1;
        const int T2 = (T + 2 < NT) ? T + 2 : 0;  // wrap: staged, never read
        const int T3 = (T + 3 < NT) ? T + 3 : 0;

        // ---- Ph1: tile T (buf0) mh0 kk0 ; stage A1(T+1) ----
        READ_A(0, 0, 0); READ_B(0, 0);
        STAGE_A(T1, 1, 16384);
        BAR(); LGKM0();
        MFMA16(0);
        BAR();

        // ---- Ph2: tile T mh1 kk0 ; stage B0(T+2) ----
        READ_A(0, 0, 1);
        STAGE_B(T2, 0, 0);
        BAR(); LGKM0();
        MFMA16(4);
        BAR();

        // ---- Ph3: tile T mh0 kk1 ; stage A0(T+2) ----
        READ_A(0, 1, 0); READ_B(0, 1);
        STAGE_A(T2, 0, 0);
        BAR(); LGKM0();
        MFMA16(0);
        BAR();

        // ---- Ph4: tile T mh1 kk1 ; stage B1(T+2) ; vmcnt publishes tile T+1 ----
        READ_A(0, 1, 1);
        STAGE_B(T2, 1, 0);
        VM6BAR(); LGKM0();
        MFMA16(4);
        BAR();

        // ---- Ph5: tile T+1 (buf1) mh0 kk0 ; stage A1(T+2) ----
        READ_A(16384, 0, 0); READ_B(16384, 0);
        STAGE_A(T2, 1, 0);
        BAR(); LGKM0();
        MFMA16(0);
        BAR();

        // ---- Ph6: tile T+1 mh1 kk0 ; stage B0(T+3) ----
        READ_A(16384, 0, 1);
        STAGE_B(T3, 0, 16384);
        BAR(); LGKM0();
        MFMA16(4);
        BAR();

        // ---- Ph7: tile T+1 mh0 kk1 ; stage A0(T+3) ----
        READ_A(16384, 1, 0); READ_B(16384, 1);
        STAGE_A(T3, 0, 16384);
        BAR(); LGKM0();
        MFMA16(0);
        BAR();

        // ---- Ph8: tile T+1 mh1 kk1 ; stage B1(T+3) ; vmcnt publishes tile T+2 ----
        READ_A(16384, 1, 1);
        STAGE_B(T3, 1, 16384);
        VM6BAR(); LGKM0();
        MFMA16(4);
        BAR();
    }

    // ---- epilogue ----
    const int crow0 = brow + wm * 128 + (lane >> 4) * 4;
    const int ccol0 = bcol + wn * 64 + (lane & 15);
    float bv[4];
    #pragma unroll
    for (int n = 0; n < 4; ++n) bv[n] = bias[ccol0 + n * 16];
    #pragma unroll
    for (int m = 0; m < 8; ++m) {
        #pragma unroll
        for (int n = 0; n < 4; ++n) {
            #pragma unroll
            for (int j = 0; j < 4; ++j) {
                int row = crow0 + m * 16 + j;
                C[(long)row * OUT_DIM + ccol0 + n * 16] = acc[m][n][j] + bv[n];
            }
        }
    }
}

extern "C" void kernel_launch(void* const* d_in, const int* in_sizes, int n_in,
                              void* d_out, int out_size, void* d_ws, size_t ws_size,
                              hipStream_t stream) {
    const float* x      = (const float*)d_in[0];
    const float* grid   = (const float*)d_in[1];
    const float* coeffs = (const float*)d_in[2];
    const float* alive  = (const float*)d_in[3];
    const float* proj_w = (const float*)d_in[4];
    const float* proj_b = (const float*)d_in[5];
    const float* res_w  = (const float*)d_in[6];
    float* out = (float*)d_out;

    char* w = (char*)d_ws;
    size_t a_bytes = (size_t)M_DIM * KCAT * sizeof(u16);     // 64 MiB
    size_t b_bytes = (size_t)OUT_DIM * KCAT * sizeof(u16);   // 4 MiB
    u16* Abf   = (u16*)w;
    u16* Bw    = (u16*)(w + a_bytes);
    float* pmc = (float*)(w + a_bytes + b_bytes);
    float* pgmin  = pmc + IN_DIM * K_KNOTS;
    float* pscale = pgmin + IN_DIM;

    prep_kernel<<<(IN_DIM + 255) / 256, 256, 0, stream>>>(grid, coeffs, alive,
                                                          pmc, pgmin, pscale);
    conv_w_kernel<<<OUT_DIM / 16, 256, 0, stream>>>(proj_w, res_w, Bw);
    build_a_kernel<<<M_DIM / 16, 256, 0, stream>>>(x, pmc, pgmin, pscale, Abf);
    gemm_kernel<<<(M_DIM / 256) * (OUT_DIM / 256), 512, 0, stream>>>(Abf, Bw, proj_b, out);
}

// Round 8
// 108.445 us; speedup vs baseline: 1.1794x; 1.0580x over previous
//
#include <hip/hip_runtime.h>
#include <hip/hip_bf16.h>

typedef unsigned short u16;
typedef float f32x4 __attribute__((ext_vector_type(4)));
typedef __bf16 bf16x8 __attribute__((ext_vector_type(8)));
typedef u16 u16x8 __attribute__((ext_vector_type(8)));

#define M_DIM 16384
#define IN_DIM 1024
#define OUT_DIM 1024
#define K_KNOTS 12
#define KCAT 2048   // concatenated K dimension

// Fragment-tiled global layout for A and B (unchanged from R7):
//   X_tiled[(g16*64 + kc)*512 + l*8 + e] = X[g16*16 + (l&15)][kc*32 + (l>>4)*8 + e]
// one wave's global_load_lds (lane*16B) stages one MFMA frag from a
// CONTIGUOUS 1KB global range.

// ---- helpers ----
__device__ __forceinline__ u16 f2bf(float f) {
    unsigned int u = __builtin_bit_cast(unsigned int, f);
    u = u + 0x7FFFu + ((u >> 16) & 1u);   // RNE
    return (u16)(u >> 16);
}

__device__ __forceinline__ void gload_lds16(const void* g, void* l) {
    __builtin_amdgcn_global_load_lds(
        (const __attribute__((address_space(1))) unsigned int*)g,
        (__attribute__((address_space(3))) unsigned int*)l, 16, 0, 0);
}

// ---- kernel 1: per-feature knot prep (sort + sigmoid mask) ----
__global__ void prep_kernel(const float* __restrict__ grid,
                            const float* __restrict__ coeffs,
                            const float* __restrict__ alive,
                            float* __restrict__ pmc,     // [IN][12]
                            float* __restrict__ pgmin,   // [IN]
                            float* __restrict__ pscale)  // [IN]
{
    int i = blockIdx.x * blockDim.x + threadIdx.x;
    if (i >= IN_DIM) return;
    float g[K_KNOTS], c[K_KNOTS], a[K_KNOTS];
    for (int k = 0; k < K_KNOTS; ++k) {
        g[k] = grid[i * K_KNOTS + k];
        c[k] = coeffs[i * K_KNOTS + k];
        a[k] = alive[i * K_KNOTS + k];
    }
    for (int k = 1; k < K_KNOTS; ++k) {
        float gk = g[k], ck = c[k], ak = a[k];
        int j = k - 1;
        while (j >= 0 && g[j] > gk) {
            g[j + 1] = g[j]; c[j + 1] = c[j]; a[j + 1] = a[j]; --j;
        }
        g[j + 1] = gk; c[j + 1] = ck; a[j + 1] = ak;
    }
    for (int k = 0; k < K_KNOTS; ++k)
        pmc[i * K_KNOTS + k] = c[k] / (1.0f + expf(-a[k]));
    pgmin[i] = g[0];
    pscale[i] = (float)(K_KNOTS - 1) / fmaxf(g[K_KNOTS - 1] - g[0], 1e-6f);
}

// ---- kernel 2: pack [proj_w | res_w] into frag-tiled bf16 B (64 n16-groups) ----
__global__ __launch_bounds__(256) void conv_w_kernel(
    const float* __restrict__ pw, const float* __restrict__ rw,
    u16* __restrict__ Bw)
{
    const int n16 = blockIdx.x;       // 0..63
    const int tid = threadIdx.x;
    #pragma unroll 1
    for (int j = 0; j < 16; ++j) {
        int s = j * 256 + tid;        // 0..4095
        int kc = s >> 6, l = s & 63;
        int row = n16 * 16 + (l & 15);
        int k = kc * 32 + ((l >> 4) & 3) * 8;
        const float* src = (k < IN_DIM) ? &pw[(long)row * IN_DIM + k]
                                        : &rw[(long)row * IN_DIM + (k - IN_DIM)];
        float4 v0 = *(const float4*)src;
        float4 v1 = *(const float4*)(src + 4);
        u16x8 ov;
        ov[0] = f2bf(v0.x); ov[1] = f2bf(v0.y); ov[2] = f2bf(v0.z); ov[3] = f2bf(v0.w);
        ov[4] = f2bf(v1.x); ov[5] = f2bf(v1.y); ov[6] = f2bf(v1.z); ov[7] = f2bf(v1.w);
        *(u16x8*)&Bw[((long)n16 * 64 + kc) * 512 + l * 8] = ov;
    }
}

// ---- kernel 3: build A = [spline(x) | x] frag-tiled, 64 rows/block ----
// 512 threads; params loaded once, amortized over 4 m16-groups.
#define XT_STR 260   // 256 + 4 pad floats

__global__ __launch_bounds__(512) void build_a_kernel(
    const float* __restrict__ x,
    const float* __restrict__ pmc,
    const float* __restrict__ pgmin,
    const float* __restrict__ pscale,
    u16* __restrict__ Abf)
{
    __shared__ float s_mc[IN_DIM * K_KNOTS];
    __shared__ float s_gmin[IN_DIM];
    __shared__ float s_scale[IN_DIM];
    __shared__ float xt[16 * XT_STR];
    const int tid = threadIdx.x;
    for (int i = tid; i < IN_DIM * K_KNOTS; i += 512) s_mc[i] = pmc[i];
    for (int i = tid; i < IN_DIM; i += 512) { s_gmin[i] = pgmin[i]; s_scale[i] = pscale[i]; }

    #pragma unroll 1
    for (int g = 0; g < 4; ++g) {
        const int m16 = blockIdx.x * 4 + g;
        #pragma unroll 1
        for (int c0 = 0; c0 < IN_DIM; c0 += 256) {
            __syncthreads();   // params ready (first iter); WAR on xt (rest)

            // phase A: coalesced x load -> xt (16 rows x 256 cols)
            #pragma unroll
            for (int p = 0; p < 2; ++p) {
                int idx = p * 512 + tid;
                int r = idx >> 6, lc = (idx & 63) * 4;
                float4 v = *(const float4*)&x[(long)(m16 * 16 + r) * IN_DIM + c0 + lc];
                *(float4*)&xt[r * XT_STR + lc] = v;
            }
            __syncthreads();

            // phase B: frag-ordered LDS reads, spline + copy, coalesced stores
            {
                int kc_l = tid >> 6, l = tid & 63;
                int r = l & 15;
                int cb = kc_l * 32 + ((l >> 4) & 3) * 8;
                const float* xp = &xt[r * XT_STR + cb];
                float4 v0 = *(const float4*)xp;
                float4 v1 = *(const float4*)(xp + 4);
                float xs[8] = {v0.x, v0.y, v0.z, v0.w, v1.x, v1.y, v1.z, v1.w};
                u16x8 so, co;
                #pragma unroll
                for (int e = 0; e < 8; ++e) {
                    int i = c0 + cb + e;
                    float xx = xs[e];
                    float xn = (xx - s_gmin[i]) * s_scale[i];
                    xn = fminf(fmaxf(xn, 0.0f), (float)(K_KNOTS - 1));
                    int li = (int)xn;
                    if (li > K_KNOTS - 2) li = K_KNOTS - 2;
                    float frac = xn - (float)li;
                    float cl = s_mc[i * K_KNOTS + li];
                    float cr = s_mc[i * K_KNOTS + li + 1];
                    so[e] = f2bf(cl + frac * (cr - cl));
                    co[e] = f2bf(xx);
                }
                long kcS = (long)m16 * 64 + (c0 >> 5) + kc_l;   // spline half
                *(u16x8*)&Abf[kcS * 512 + l * 8] = so;
                *(u16x8*)&Abf[(kcS + 32) * 512 + l * 8] = co;   // copy half
            }
        }
    }
}

// ---- kernel 4: 128x256 bf16 GEMM, TBK=32, 2 blocks/CU ----
// 8 waves (2M x 4N, per-wave 64x64), 48 KiB double-buffered LDS, one phase
// per K-tile: {8 ds_read -> lgkm0 -> 16 MFMA -> bar -> stage T+2 -> vmcnt(3)+bar}.
#define TBK 32
#define NT (KCAT / TBK)   // 64 K-tiles
#define MSTR 32768L       // m16/n16-group stride in frag-tiled layout

#define BAR()     asm volatile("s_barrier" ::: "memory")
#define VM3BAR()  asm volatile("s_waitcnt vmcnt(3)\ns_barrier" ::: "memory")
#define LGKM0()   do { asm volatile("s_waitcnt lgkmcnt(0)" ::: "memory"); \
                       __builtin_amdgcn_sched_barrier(0); } while (0)

// LDS map (u16): A buf b @ b*4096 (8 frags x 512); B buf b @ 8192 + b*8192
// (16 frags x 512). Total 24576 u16 = 48 KiB. Lane-order frags (conflict-free).
#define STAGE2(T, cb) do { \
    gload_lds16(pAf +          ((long)(T)) * 512, &lds[(cb) * 4096 + tid * 8]); \
    gload_lds16(pBf +          ((long)(T)) * 512, &lds[8192 + (cb) * 8192 + tid * 8]); \
    gload_lds16(pBf + 8*MSTR + ((long)(T)) * 512, &lds[8192 + (cb) * 8192 + 4096 + tid * 8]); } while (0)

__global__ __launch_bounds__(512, 4) void gemm_kernel(
    const u16* __restrict__ A,   // frag-tiled, 1024 m16-groups
    const u16* __restrict__ B,   // frag-tiled, 64 n16-groups
    const float* __restrict__ bias,
    float* __restrict__ C)
{
    __shared__ __align__(16) u16 lds[24576];   // 48 KiB

    const int tid  = threadIdx.x;
    const int lane = tid & 63;
    const int wave = tid >> 6;
    const int wm   = wave >> 2;   // 0..1
    const int wn   = wave & 3;    // 0..3

    // bijective XCD swizzle (nwg = 512, divisible by 8)
    int wgid = (blockIdx.x & 7) * 64 + (blockIdx.x >> 3);
    const int brow = (wgid >> 2) * 128;
    const int bcol = (wgid & 3) * 256;

    // contiguous staging sources: wave w stages A frag w, B frags w and w+8
    const u16* pAf = A + ((long)(brow >> 4) + wave) * MSTR + lane * 8;
    const u16* pBf = B + ((long)(bcol >> 4) + wave) * MSTR + lane * 8;

    const int loff = lane * 8;    // lane-order frag read

    f32x4 acc[4][4] = {};
    bf16x8 af[4], bfr[4];

    // prologue: tile 0 -> buf0, tile 1 -> buf1 (3 gloads/wave each)
    STAGE2(0, 0);
    STAGE2(1, 1);
    VM3BAR();   // tile 0 complete; tile 1's 3 ops may remain in flight

    #pragma unroll 1
    for (int t = 0; t < NT; ++t) {
        const int cb = t & 1;
        const int ab = cb * 4096;
        const int bb = 8192 + cb * 8192;

        #pragma unroll
        for (int m_ = 0; m_ < 4; ++m_)
            af[m_] = *(const bf16x8*)&lds[ab + (wm * 4 + m_) * 512 + loff];
        #pragma unroll
        for (int n_ = 0; n_ < 4; ++n_)
            bfr[n_] = *(const bf16x8*)&lds[bb + (wn * 4 + n_) * 512 + loff];
        LGKM0();
        __builtin_amdgcn_s_setprio(1);
        #pragma unroll
        for (int m_ = 0; m_ < 4; ++m_)
            #pragma unroll
            for (int n_ = 0; n_ < 4; ++n_)
                acc[m_][n_] = __builtin_amdgcn_mfma_f32_16x16x32_bf16(
                    af[m_], bfr[n_], acc[m_][n_], 0, 0, 0);
        __builtin_amdgcn_s_setprio(0);
        BAR();                       // all waves done reading buf cb

        const int T2 = (t + 2) & 63; // wrap: staged, never read; stays in-bounds
        STAGE2(T2, cb);
        VM3BAR();                    // tile t+1 (other buf) complete for all waves
    }

    // ---- epilogue ----
    const int crow0 = brow + wm * 64 + (lane >> 4) * 4;
    const int ccol0 = bcol + wn * 64 + (lane & 15);
    float bv[4];
    #pragma unroll
    for (int n = 0; n < 4; ++n) bv[n] = bias[ccol0 + n * 16];
    #pragma unroll
    for (int m = 0; m < 4; ++m) {
        #pragma unroll
        for (int n = 0; n < 4; ++n) {
            #pragma unroll
            for (int j = 0; j < 4; ++j) {
                int row = crow0 + m * 16 + j;
                C[(long)row * OUT_DIM + ccol0 + n * 16] = acc[m][n][j] + bv[n];
            }
        }
    }
}

extern "C" void kernel_launch(void* const* d_in, const int* in_sizes, int n_in,
                              void* d_out, int out_size, void* d_ws, size_t ws_size,
                              hipStream_t stream) {
    const float* x      = (const float*)d_in[0];
    const float* grid   = (const float*)d_in[1];
    const float* coeffs = (const float*)d_in[2];
    const float* alive  = (const float*)d_in[3];
    const float* proj_w = (const float*)d_in[4];
    const float* proj_b = (const float*)d_in[5];
    const float* res_w  = (const float*)d_in[6];
    float* out = (float*)d_out;

    char* w = (char*)d_ws;
    size_t a_bytes = (size_t)M_DIM * KCAT * sizeof(u16);     // 64 MiB
    size_t b_bytes = (size_t)OUT_DIM * KCAT * sizeof(u16);   // 4 MiB
    u16* Abf   = (u16*)w;
    u16* Bw    = (u16*)(w + a_bytes);
    float* pmc = (float*)(w + a_bytes + b_bytes);
    float* pgmin  = pmc + IN_DIM * K_KNOTS;
    float* pscale = pgmin + IN_DIM;

    prep_kernel<<<(IN_DIM + 255) / 256, 256, 0, stream>>>(grid, coeffs, alive,
                                                          pmc, pgmin, pscale);
    conv_w_kernel<<<OUT_DIM / 16, 256, 0, stream>>>(proj_w, res_w, Bw);
    build_a_kernel<<<M_DIM / 64, 512, 0, stream>>>(x, pmc, pgmin, pscale, Abf);
    gemm_kernel<<<(M_DIM / 128) * (OUT_DIM / 256), 512, 0, stream>>>(Abf, Bw, proj_b, out);
}